// Round 9
// baseline (704.127 us; speedup 1.0000x reference)
//
#include <hip/hip_runtime.h>
#include <hip/hip_cooperative_groups.h>

namespace cg = cooperative_groups;

typedef unsigned short u16;
typedef unsigned int u32;

#define B_ 2
#define L_ 4096
#define D_ 512
#define H_ 8
#define E_ 64
#define M_ (B_*L_)        // 8192 rows
#define TD (3*D_)         // 1536
#define NCH (L_/64)       // 64 chunks of 64 per sequence
#define BH (B_*H_)        // 16

typedef short bf16x8 __attribute__((ext_vector_type(8)));
typedef float f32x4 __attribute__((ext_vector_type(4)));

__device__ __forceinline__ float bf2f(u16 u){ return __uint_as_float(((u32)u)<<16); }
__device__ __forceinline__ u16 f2bf(float f){
  u32 u = __float_as_uint(f);
  u32 r = u + 0x7FFFu + ((u>>16)&1u);   // RNE; inputs finite
  return (u16)(r>>16);
}
__device__ __forceinline__ float elu1(float v){ return v>0.f ? v+1.f : expf(v); }

__device__ __forceinline__ void async_ld16(const u16* g, u16* l){
  __builtin_amdgcn_global_load_lds(
      (const __attribute__((address_space(1))) void*)g,
      (__attribute__((address_space(3))) void*)l, 16, 0, 0);
}

// ---------------- K1: decay logits + x->bf16 + weight conversions ----------------
__global__ __launch_bounds__(256) void decay_conv_kernel(const float* __restrict__ x,
    const float* __restrict__ dw, const float* __restrict__ db,
    const float* __restrict__ qw, const float* __restrict__ ow,
    float* __restrict__ ll, u16* __restrict__ xb,
    u16* __restrict__ qwb, u16* __restrict__ owb)
{
  int blk = blockIdx.x;
  if (blk < 2048){
    int wv = threadIdx.x>>6, lane = threadIdx.x&63;
    int m = blk*4 + wv;
    float xr[8];
    #pragma unroll
    for (int i=0;i<8;i++) xr[i] = x[(size_t)m*D_ + lane + 64*i];
    #pragma unroll
    for (int i=0;i<8;i++) xb[(size_t)m*D_ + lane + 64*i] = f2bf(xr[i]);
    int b = m >> 12, l = m & (L_-1);
    for (int h=0; h<H_; h++){
      float acc = 0.f;
      #pragma unroll
      for (int i=0;i<8;i++) acc += xr[i]*dw[h*D_ + lane + 64*i];
      #pragma unroll
      for (int off=32; off>0; off>>=1) acc += __shfl_xor(acc, off);
      if (lane == h){
        float z = acc + db[h];
        float lam = 0.9f + 0.1f/(1.f + expf(-z));
        ll[((b*H_+h)*L_) + l] = logf(lam);
      }
    }
  } else {
    int gid = (blk-2048)*256 + threadIdx.x;
    const float* src; u16* dst; int off;
    if (gid < 196608){ src = qw; dst = qwb; off = gid; }
    else { src = ow; dst = owb; off = gid - 196608; }
    float4 v = ((const float4*)src)[off];
    ushort4 o; o.x=f2bf(v.x); o.y=f2bf(v.y); o.z=f2bf(v.z); o.w=f2bf(v.w);
    ((ushort4*)dst)[off] = o;
  }
}

// ---------------- K2: inclusive scan over L (shfl-based), clip to [-50,50] ----------------
__global__ __launch_bounds__(256) void scan_kernel(const float* __restrict__ ll,
    float* __restrict__ cb)
{
  int bh = blockIdx.x, t = threadIdx.x;
  int lane = t & 63, wv = t >> 6;
  const float* p = ll + (size_t)bh*L_ + t*16;
  float s[16];
  #pragma unroll
  for (int q=0;q<4;q++){
    float4 v = *(const float4*)(p + q*4);
    s[q*4+0]=v.x; s[q*4+1]=v.y; s[q*4+2]=v.z; s[q*4+3]=v.w;
  }
  #pragma unroll
  for (int i=1;i<16;i++) s[i] += s[i-1];
  float tot = s[15];
  float ws = tot;
  #pragma unroll
  for (int off=1; off<64; off<<=1){
    float tmp = __shfl_up(ws, off);
    if (lane >= off) ws += tmp;
  }
  __shared__ float wsum[4];
  if (lane == 63) wsum[wv] = ws;
  __syncthreads();
  float base = 0.f;
  #pragma unroll
  for (int w2=0; w2<3; w2++) if (w2 < wv) base += wsum[w2];
  float ex = base + ws - tot;
  float* c = cb + (size_t)bh*L_ + t*16;
  #pragma unroll
  for (int i=0;i<16;i++) c[i] = fminf(50.f, fmaxf(-50.f, ex + s[i]));
}

// ---------------- MFMA GEMM: C[m][n] = sum_k A[m][k]*W[n][k] + bias[n] ----------------
template<bool OB>
__global__ __launch_bounds__(256) void gemm_mfma(const u16* __restrict__ A,
    const u16* __restrict__ W, const float* __restrict__ bias,
    void* __restrict__ Cv, int M, int N, int K)
{
  __shared__ u16 As[128*32];
  __shared__ u16 Bs[128*32];
  int n0 = blockIdx.x*128, m0 = blockIdx.y*128;
  int t = threadIdx.x, wave = t>>6, lane = t&63;
  int wm = (wave>>1)*64, wn = (wave&1)*64;
  f32x4 acc[4][4] = {};
  int srow = wave*32 + (lane>>2);
  int scol = (lane&3)*8;
  const u16* gA = A + (size_t)(m0+srow)*K + scol;
  const u16* gB = W + (size_t)(n0+srow)*K + scol;
  u16* lA = As + wave*1024;
  u16* lB = Bs + wave*1024;
  int q8 = (lane>>4)*8, r16 = lane&15;
  for (int k0=0; k0<K; k0+=32){
    async_ld16(gA + k0,                lA);
    async_ld16(gA + k0 + 16*(size_t)K, lA + 512);
    async_ld16(gB + k0,                lB);
    async_ld16(gB + k0 + 16*(size_t)K, lB + 512);
    __syncthreads();
    bf16x8 af[4], bfr[4];
    #pragma unroll
    for (int i=0;i<4;i++) af[i]  = *(const bf16x8*)&As[(wm + i*16 + r16)*32 + q8];
    #pragma unroll
    for (int j=0;j<4;j++) bfr[j] = *(const bf16x8*)&Bs[(wn + j*16 + r16)*32 + q8];
    #pragma unroll
    for (int i=0;i<4;i++)
      #pragma unroll
      for (int j=0;j<4;j++)
        acc[i][j] = __builtin_amdgcn_mfma_f32_16x16x32_bf16(af[i], bfr[j], acc[i][j], 0,0,0);
    __syncthreads();
  }
  #pragma unroll
  for (int i=0;i<4;i++){
    int row = m0 + wm + i*16 + (lane>>4)*4;
    #pragma unroll
    for (int j=0;j<4;j++){
      int col = n0 + wn + j*16 + r16;
      float bv = bias[col];
      #pragma unroll
      for (int r=0;r<4;r++){
        float val = acc[i][j][r] + bv;
        if (OB) ((u16*)Cv)[(size_t)(row+r)*N + col] = f2bf(val);
        else    ((float*)Cv)[(size_t)(row+r)*N + col] = val;
      }
    }
  }
}

// ---------------- K4 (coop): fused chunk pipeline ----------------
__global__ __launch_bounds__(256, 4) void chunk_fused_kernel(
    const u16* __restrict__ qkvb, const float* __restrict__ cb,
    u16* __restrict__ Stc, float* __restrict__ ksc, u16* __restrict__ attn)
{
  cg::grid_group grid = cg::this_grid();
  int bid = blockIdx.x;
  int bh = bid >> 6, ch = bid & 63;
  int b = bh >> 3, h = bh & 7;
  __shared__ u16 ql[4096];
  __shared__ u16 kl[4096];
  __shared__ u16 vtl[4096];
  __shared__ u16 scr[4096];
  __shared__ float kp[64], den4[256], den[64];
  int t = threadIdx.x, w = t>>6, lane = t&63;
  int r16 = lane & 15, q8 = (lane>>4)*8;
  size_t mbase = (size_t)b*L_ + ch*64;

  // ---- phase 1 ----
  #pragma unroll
  for (int i=0;i<2;i++){
    int idx = t + 256*i;
    int l = idx>>3, e0 = (idx&7)*8;
    int eh = e0>>5, e31 = e0&31;
    int jh = l>>5, l31 = l&31;
    float c = cb[(size_t)bh*L_ + ch*64 + l];
    float eqc = expf(c)*0.125f, ekc = expf(-c);
    const u16* src = qkvb + (mbase+l)*TD + h*64 + e0;
    u16 in[8], o[8];
    *(ushort4*)&in[0] = *(const ushort4*)(src);
    *(ushort4*)&in[4] = *(const ushort4*)(src+4);
    #pragma unroll
    for (int j=0;j<8;j++) o[j] = f2bf(elu1(bf2f(in[j]))*eqc);
    *(ushort4*)&ql[(eh*64+l)*32 + e31]     = *(ushort4*)&o[0];
    *(ushort4*)&ql[(eh*64+l)*32 + e31 + 4] = *(ushort4*)&o[4];
    *(ushort4*)&in[0] = *(const ushort4*)(src + D_);
    *(ushort4*)&in[4] = *(const ushort4*)(src + D_ + 4);
    #pragma unroll
    for (int j=0;j<8;j++) o[j] = f2bf(elu1(bf2f(in[j]))*ekc);
    *(ushort4*)&kl[(eh*64+l)*32 + e31]     = *(ushort4*)&o[0];
    *(ushort4*)&kl[(eh*64+l)*32 + e31 + 4] = *(ushort4*)&o[4];
    #pragma unroll
    for (int j=0;j<8;j++) scr[(jh*64 + e0+j)*32 + l31] = o[j];
    *(ushort4*)&in[0] = *(const ushort4*)(src + 2*D_);
    *(ushort4*)&in[4] = *(const ushort4*)(src + 2*D_ + 4);
    #pragma unroll
    for (int j=0;j<8;j++) vtl[(jh*64 + e0+j)*32 + l31] = in[j];
  }
  __syncthreads();
  if (t < 64){
    float s = 0.f;
    #pragma unroll
    for (int jh2=0;jh2<2;jh2++){
      const u16* row = &scr[(jh2*64 + t)*32];
      #pragma unroll
      for (int q=0;q<32;q++) s += bf2f(row[q]);
    }
    ksc[bid*64 + t] = s;
  }
  {
    bf16x8 av[2];
    #pragma unroll
    for (int kh=0;kh<2;kh++)
      av[kh] = *(const bf16x8*)&vtl[(kh*64 + w*16 + r16)*32 + q8];
    f32x4 acc[4] = {};
    #pragma unroll
    for (int et=0;et<4;et++)
      #pragma unroll
      for (int kh=0;kh<2;kh++){
        bf16x8 bv = *(const bf16x8*)&scr[(kh*64 + et*16 + r16)*32 + q8];
        acc[et] = __builtin_amdgcn_mfma_f32_16x16x32_bf16(av[kh], bv, acc[et], 0,0,0);
      }
    #pragma unroll
    for (int et=0;et<4;et++){
      int eh = et>>1, el = (et&1)*16 + r16;
      #pragma unroll
      for (int r=0;r<4;r++){
        int f = w*16 + (lane>>4)*4 + r;
        Stc[((size_t)bid*2 + eh)*2048 + f*32 + el] = f2bf(acc[et][r]);
      }
    }
  }
  __threadfence();
  grid.sync();
  __threadfence();

  // ---- phase 2 ----
  int gid = bid*256 + t;
  if (gid < 32768){
    int pbh = gid >> 11, e2 = gid & 2047;
    u32* p = (u32*)Stc + (size_t)pbh*131072 + e2;
    float r0 = 0.f, r1 = 0.f;
    #pragma unroll 4
    for (int c2=0; c2<NCH; c2++){
      u32 v = p[c2*2048];
      float lo = bf2f((u16)(v & 0xffffu));
      float hi = bf2f((u16)(v >> 16));
      p[c2*2048] = (u32)f2bf(r0) | ((u32)f2bf(r1) << 16);
      r0 += lo; r1 += hi;
    }
  }
  if (gid < BH*64){
    int pbh = gid >> 6, e = gid & 63;
    float* kpp = ksc + pbh*4096 + e;
    float kr = 0.f;
    #pragma unroll 4
    for (int c2=0; c2<NCH; c2++){
      float v = kpp[c2*64]; kpp[c2*64] = kr; kr += v;
    }
  }
  __threadfence();
  grid.sync();
  __threadfence();

  // ---- phase 3 ----
  if (t < 64) kp[t] = ksc[bid*64 + t];
  bf16x8 stf[2][4];
  #pragma unroll
  for (int eh=0;eh<2;eh++)
    #pragma unroll
    for (int ft=0;ft<4;ft++)
      stf[eh][ft] = *(const bf16x8*)&Stc[(size_t)bid*4096 + (eh*64 + ft*16 + r16)*32 + q8];
  __syncthreads();
  bf16x8 aq[2];
  #pragma unroll
  for (int eh=0;eh<2;eh++)
    aq[eh] = *(const bf16x8*)&ql[(eh*64 + w*16 + r16)*32 + q8];
  f32x4 accA[4] = {};
  #pragma unroll
  for (int jt=0;jt<4;jt++)
    #pragma unroll
    for (int eh=0;eh<2;eh++){
      bf16x8 bv = *(const bf16x8*)&kl[(eh*64 + jt*16 + r16)*32 + q8];
      accA[jt] = __builtin_amdgcn_mfma_f32_16x16x32_bf16(aq[eh], bv, accA[jt], 0,0,0);
    }
  int l4 = t>>2, q4 = t&3;
  float dkp = 0.f;
  {
    int eh = q4>>1, el0 = (q4&1)*16;
    bf16x8 x1 = *(const bf16x8*)&ql[(eh*64 + l4)*32 + el0];
    bf16x8 x2 = *(const bf16x8*)&ql[(eh*64 + l4)*32 + el0 + 8];
    #pragma unroll
    for (int i=0;i<8;i++)
      dkp += bf2f((u16)x1[i])*kp[q4*16+i] + bf2f((u16)x2[i])*kp[q4*16+8+i];
  }
  __syncthreads();
  #pragma unroll
  for (int jt=0;jt<4;jt++)
    #pragma unroll
    for (int r=0;r<4;r++){
      int lr = w*16 + ((lane>>4)<<2) + r;
      int j  = jt*16 + r16;
      scr[((jt>>1)*64 + lr)*32 + (jt&1)*16 + r16] = (j <= lr) ? f2bf(accA[jt][r]) : (u16)0;
    }
  __syncthreads();
  float dA = 0.f;
  {
    int jh2 = q4>>1, jl0 = (q4&1)*16;
    bf16x8 y1 = *(const bf16x8*)&scr[(jh2*64 + l4)*32 + jl0];
    bf16x8 y2 = *(const bf16x8*)&scr[(jh2*64 + l4)*32 + jl0 + 8];
    #pragma unroll
    for (int i=0;i<8;i++) dA += bf2f((u16)y1[i]) + bf2f((u16)y2[i]);
  }
  den4[t] = dkp + dA;
  __syncthreads();
  if (t < 64) den[t] = den4[t*4] + den4[t*4+1] + den4[t*4+2] + den4[t*4+3] + 1e-6f;
  bf16x8 aA[2];
  #pragma unroll
  for (int jh=0;jh<2;jh++)
    aA[jh] = *(const bf16x8*)&scr[(jh*64 + w*16 + r16)*32 + q8];
  f32x4 acc[4] = {};
  #pragma unroll
  for (int ft=0;ft<4;ft++){
    #pragma unroll
    for (int jh=0;jh<2;jh++){
      bf16x8 bv = *(const bf16x8*)&vtl[(jh*64 + ft*16 + r16)*32 + q8];
      acc[ft] = __builtin_amdgcn_mfma_f32_16x16x32_bf16(aA[jh], bv, acc[ft], 0,0,0);
    }
    #pragma unroll
    for (int eh=0;eh<2;eh++)
      acc[ft] = __builtin_amdgcn_mfma_f32_16x16x32_bf16(aq[eh], stf[eh][ft], acc[ft], 0,0,0);
  }
  __syncthreads();
  float inv[4];
  #pragma unroll
  for (int r=0;r<4;r++) inv[r] = 1.f / den[w*16 + ((lane>>4)<<2) + r];
  #pragma unroll
  for (int ft=0;ft<4;ft++)
    #pragma unroll
    for (int r=0;r<4;r++){
      int lr = w*16 + ((lane>>4)<<2) + r;
      attn[(mbase + lr)*D_ + h*64 + ft*16 + r16] = f2bf(acc[ft][r]*inv[r]);
    }
}

// ========== Fallback path: round-7 verified 3-kernel chunk pipeline ==========
__global__ __launch_bounds__(256) void transform_sums_kernel(const u16* __restrict__ qkvb,
    const float* __restrict__ cb, u16* __restrict__ qc, u16* __restrict__ kc,
    u16* __restrict__ vtc, u16* __restrict__ Stc, float* __restrict__ ksc)
{
  int bid = blockIdx.x;
  int bh = bid >> 6, ch = bid & 63;
  int b = bh >> 3, h = bh & 7;
  __shared__ u16 Ks[64*68];
  __shared__ u16 Vs[64*68];
  __shared__ u16 Ktl[4096];
  __shared__ u16 Vtl[4096];
  __shared__ float ksr[256];
  int t = threadIdx.x;
  size_t mbase = (size_t)b*L_ + ch*64;
  #pragma unroll
  for (int i=0;i<2;i++){
    int idx = t + 256*i;
    int l = idx>>3, e0 = (idx&7)*8;
    int kh = e0>>5, ej = e0&31;
    float c = cb[(size_t)bh*L_ + ch*64 + l];
    float eqc = expf(c)*0.125f, ekc = expf(-c);
    const u16* src = qkvb + (mbase+l)*TD + h*64 + e0;
    u16 in[8], o[8];
    *(ushort4*)&in[0] = *(const ushort4*)(src);
    *(ushort4*)&in[4] = *(const ushort4*)(src+4);
    #pragma unroll
    for (int j=0;j<8;j++) o[j] = f2bf(elu1(bf2f(in[j]))*eqc);
    u16* qd = qc + ((size_t)bid*2 + kh)*2048 + l*32 + ej;
    *(ushort4*)qd = *(ushort4*)&o[0];
    *(ushort4*)(qd+4) = *(ushort4*)&o[4];
    *(ushort4*)&in[0] = *(const ushort4*)(src + D_);
    *(ushort4*)&in[4] = *(const ushort4*)(src + D_ + 4);
    #pragma unroll
    for (int j=0;j<8;j++) o[j] = f2bf(elu1(bf2f(in[j]))*ekc);
    u16* kd = kc + ((size_t)bid*2 + kh)*2048 + l*32 + ej;
    *(ushort4*)kd = *(ushort4*)&o[0];
    *(ushort4*)(kd+4) = *(ushort4*)&o[4];
    *(ushort4*)&Ks[l*68+e0]   = *(ushort4*)&o[0];
    *(ushort4*)&Ks[l*68+e0+4] = *(ushort4*)&o[4];
    *(ushort4*)&Vs[l*68+e0]   = *(const ushort4*)(src + 2*D_);
    *(ushort4*)&Vs[l*68+e0+4] = *(const ushort4*)(src + 2*D_ + 4);
  }
  __syncthreads();
  int e = t & 63, jq = t >> 6;
  {
    u16 kv[16], vv[16];
    float ksum = 0.f;
    #pragma unroll
    for (int jj=0;jj<16;jj++){
      int j = jq*16+jj;
      kv[jj] = Ks[j*68 + e];
      ksum += bf2f(kv[jj]);
      vv[jj] = Vs[j*68 + e];
    }
    int kh = jq>>1, jl = (jq&1)*16;
    u16* kt = &Ktl[(kh*64 + e)*32 + jl];
    u16* vt = &Vtl[(kh*64 + e)*32 + jl];
    #pragma unroll
    for (int s=0;s<4;s++){
      *(ushort4*)(kt + s*4) = *(ushort4*)&kv[s*4];
      *(ushort4*)(vt + s*4) = *(ushort4*)&vv[s*4];
    }
    ksr[t] = ksum;
  }
  __syncthreads();
  {
    *(uint4*)&vtc[(size_t)bid*4096 + t*8]        = *(const uint4*)&Vtl[t*8];
    *(uint4*)&vtc[(size_t)bid*4096 + 2048 + t*8] = *(const uint4*)&Vtl[2048 + t*8];
  }
  int w = t>>6, lane = t&63;
  int r16 = lane & 15, q8 = (lane>>4)*8;
  bf16x8 av[2];
  #pragma unroll
  for (int kh=0;kh<2;kh++)
    av[kh] = *(const bf16x8*)&Vtl[(kh*64 + w*16 + r16)*32 + q8];
  f32x4 acc[4] = {};
  #pragma unroll
  for (int et=0;et<4;et++)
    #pragma unroll
    for (int kh=0;kh<2;kh++){
      bf16x8 bv = *(const bf16x8*)&Ktl[(kh*64 + et*16 + r16)*32 + q8];
      acc[et] = __builtin_amdgcn_mfma_f32_16x16x32_bf16(av[kh], bv, acc[et], 0,0,0);
    }
  #pragma unroll
  for (int et=0;et<4;et++){
    int eh = et>>1, el = (et&1)*16 + r16;
    #pragma unroll
    for (int r=0;r<4;r++){
      int f = w*16 + (lane>>4)*4 + r;
      Stc[((size_t)bid*2 + eh)*2048 + f*32 + el] = f2bf(acc[et][r]);
    }
  }
  if (t < 64) ksc[bid*64 + t] = ksr[t] + ksr[64+t] + ksr[128+t] + ksr[192+t];
}

__global__ __launch_bounds__(256) void chunk_prefix_kernel(u16* __restrict__ Stc,
    float* __restrict__ ksc)
{
  int gid = blockIdx.x*256 + threadIdx.x;
  int bh = gid >> 11, e2 = gid & 2047;
  u32* p = (u32*)Stc + (size_t)bh*131072 + e2;
  float r0 = 0.f, r1 = 0.f;
  #pragma unroll 4
  for (int ch=0; ch<NCH; ch++){
    u32 v = p[ch*2048];
    float lo = bf2f((u16)(v & 0xffffu));
    float hi = bf2f((u16)(v >> 16));
    p[ch*2048] = (u32)f2bf(r0) | ((u32)f2bf(r1) << 16);
    r0 += lo; r1 += hi;
  }
  if (gid < BH*64){
    int bh2 = gid >> 6, e = gid & 63;
    float* kp = ksc + bh2*4096 + e;
    float kr = 0.f;
    #pragma unroll 4
    for (int ch=0; ch<NCH; ch++){
      float v = kp[ch*64]; kp[ch*64] = kr; kr += v;
    }
  }
}

__global__ __launch_bounds__(256) void chunk_out_kernel(const u16* __restrict__ qc,
    const u16* __restrict__ kc, const u16* __restrict__ vtc,
    const u16* __restrict__ Stc, const float* __restrict__ ksc,
    u16* __restrict__ attn)
{
  int bid = blockIdx.x;
  int bh = bid >> 6, ch = bid & 63;
  int b = bh >> 3, h = bh & 7;
  __shared__ u16 KV[16384];
  __shared__ u16 Ab[4096];
  __shared__ float kp[64], den4[256], den[64];
  int t = threadIdx.x, w = t>>6, lane = t&63;
  size_t mbase = (size_t)b*L_ + ch*64;
  const u16* srcs[4] = { qc, kc, vtc, Stc };
  {
    const u16* gbase = srcs[w] + (size_t)bid*4096 + lane*8;
    #pragma unroll
    for (int q=0;q<8;q++)
      async_ld16(gbase + q*512, KV + w*4096 + q*512);
  }
  if (t < 64) kp[t] = ksc[bid*64 + t];
  __syncthreads();
  const u16* Qs   = KV;
  const u16* Kb_s = KV + 4096;
  const u16* Vt_s = KV + 8192;
  const u16* St_s = KV + 12288;
  int r16 = lane & 15, q8 = (lane>>4)*8;
  bf16x8 aq[2];
  #pragma unroll
  for (int eh=0;eh<2;eh++)
    aq[eh] = *(const bf16x8*)&Qs[(eh*64 + w*16 + r16)*32 + q8];
  f32x4 accA[4] = {};
  #pragma unroll
  for (int jt=0;jt<4;jt++)
    #pragma unroll
    for (int eh=0;eh<2;eh++){
      bf16x8 bv = *(const bf16x8*)&Kb_s[(eh*64 + jt*16 + r16)*32 + q8];
      accA[jt] = __builtin_amdgcn_mfma_f32_16x16x32_bf16(aq[eh], bv, accA[jt], 0,0,0);
    }
  int l4 = t>>2, q4 = t&3;
  float dkp = 0.f;
  {
    int eh = q4>>1, el0 = (q4&1)*16;
    bf16x8 x1 = *(const bf16x8*)&Qs[(eh*64 + l4)*32 + el0];
    bf16x8 x2 = *(const bf16x8*)&Qs[(eh*64 + l4)*32 + el0 + 8];
    #pragma unroll
    for (int i=0;i<8;i++)
      dkp += bf2f((u16)x1[i])*kp[q4*16+i] + bf2f((u16)x2[i])*kp[q4*16+8+i];
  }
  #pragma unroll
  for (int jt=0;jt<4;jt++)
    #pragma unroll
    for (int r=0;r<4;r++){
      int lr = w*16 + ((lane>>4)<<2) + r;
      int j  = jt*16 + r16;
      Ab[((jt>>1)*64 + lr)*32 + (jt&1)*16 + r16] = (j <= lr) ? f2bf(accA[jt][r]) : (u16)0;
    }
  __syncthreads();
  float dA = 0.f;
  {
    int jh2 = q4>>1, jl0 = (q4&1)*16;
    bf16x8 y1 = *(const bf16x8*)&Ab[(jh2*64 + l4)*32 + jl0];
    bf16x8 y2 = *(const bf16x8*)&Ab[(jh2*64 + l4)*32 + jl0 + 8];
    #pragma unroll
    for (int i=0;i<8;i++) dA += bf2f((u16)y1[i]) + bf2f((u16)y2[i]);
  }
  den4[t] = dkp + dA;
  __syncthreads();
  if (t < 64) den[t] = den4[t*4] + den4[t*4+1] + den4[t*4+2] + den4[t*4+3] + 1e-6f;
  bf16x8 aA[2];
  #pragma unroll
  for (int jh=0;jh<2;jh++)
    aA[jh] = *(const bf16x8*)&Ab[(jh*64 + w*16 + r16)*32 + q8];
  f32x4 acc[4] = {};
  #pragma unroll
  for (int ft=0;ft<4;ft++){
    #pragma unroll
    for (int jh=0;jh<2;jh++){
      bf16x8 bv = *(const bf16x8*)&Vt_s[(jh*64 + ft*16 + r16)*32 + q8];
      acc[ft] = __builtin_amdgcn_mfma_f32_16x16x32_bf16(aA[jh], bv, acc[ft], 0,0,0);
    }
    #pragma unroll
    for (int eh=0;eh<2;eh++){
      bf16x8 bv = *(const bf16x8*)&St_s[(eh*64 + ft*16 + r16)*32 + q8];
      acc[ft] = __builtin_amdgcn_mfma_f32_16x16x32_bf16(aq[eh], bv, acc[ft], 0,0,0);
    }
  }
  __syncthreads();
  float inv[4];
  #pragma unroll
  for (int r=0;r<4;r++) inv[r] = 1.f / den[w*16 + ((lane>>4)<<2) + r];
  #pragma unroll
  for (int ft=0;ft<4;ft++)
    #pragma unroll
    for (int r=0;r<4;r++){
      int lr = w*16 + ((lane>>4)<<2) + r;
      attn[(mbase + lr)*D_ + h*64 + ft*16 + r16] = f2bf(acc[ft][r]*inv[r]);
    }
}

// ---------------- K8: RMSNorm + scale (bf16 mid -> fp32 out) ----------------
__global__ __launch_bounds__(256) void rmsnorm_kernel(const u16* __restrict__ mid,
    const float* __restrict__ scale, float* __restrict__ out)
{
  int m = blockIdx.x, t = threadIdx.x;
  const u16* row = mid + (size_t)m*D_;
  float v0 = bf2f(row[t]), v1 = bf2f(row[t+256]);
  float ss = v0*v0 + v1*v1;
  #pragma unroll
  for (int off=32; off>0; off>>=1) ss += __shfl_xor(ss, off);
  __shared__ float red[4];
  if ((t&63)==0) red[t>>6] = ss;
  __syncthreads();
  float tot = red[0]+red[1]+red[2]+red[3];
  float r = rsqrtf(tot*(1.f/512.f) + 1e-8f);
  out[(size_t)m*D_ + t]       = v0*r*scale[t];
  out[(size_t)m*D_ + t + 256] = v1*r*scale[t+256];
}

extern "C" void kernel_launch(void* const* d_in, const int* in_sizes, int n_in,
                              void* d_out, int out_size, void* d_ws, size_t ws_size,
                              hipStream_t stream)
{
  const float* x     = (const float*)d_in[0];
  const float* w_qkv = (const float*)d_in[1];
  const float* b_qkv = (const float*)d_in[2];
  const float* w_out = (const float*)d_in[3];
  const float* b_out = (const float*)d_in[4];
  const float* w_dec = (const float*)d_in[5];
  const float* b_dec = (const float*)d_in[6];
  const float* gnorm = (const float*)d_in[7];
  float* out = (float*)d_out;

  char* ws = (char*)d_ws;
  u16*   qkvb = (u16*)(ws);                    // 25,165,824
  u16*   Stc  = (u16*)(ws + 25165824);         //  8,388,608
  float* ksc  = (float*)(ws + 33554432);       //    262,144
  float* ll   = (float*)(ws + 33816576);       //    262,144
  float* cb   = (float*)(ws + 34078720);       //    262,144
  u16*   xb   = (u16*)(ws + 34340864);         //  8,388,608
  u16*   qwb  = (u16*)(ws + 42729472);         //  1,572,864
  u16*   owb  = (u16*)(ws + 44302336);         //    524,288
  u16*   qc   = (u16*)(ws + 44826624);         //  8,388,608 (fallback)
  u16*   kc   = (u16*)(ws + 53215232);         //  8,388,608 (fallback)
  u16*   vtc  = (u16*)(ws + 61603840);         //  8,388,608 (fallback) total 69,992,448
  u16*   midb = qkvb;
  u16*   attn = xb;

  decay_conv_kernel<<<dim3(3072), dim3(256), 0, stream>>>(x, w_dec, b_dec, w_qkv, w_out,
                                                          ll, xb, qwb, owb);
  scan_kernel<<<dim3(BH), dim3(256), 0, stream>>>(ll, cb);
  gemm_mfma<true><<<dim3(TD/128, M_/128), dim3(256), 0, stream>>>(xb, qwb, b_qkv, qkvb, M_, TD, D_);
  {
    const u16*  a0 = qkvb;
    const float* a1 = cb;
    u16*  a2 = Stc;
    float* a3 = ksc;
    u16*  a4 = attn;
    void* kargs[5] = { &a0, &a1, &a2, &a3, &a4 };
    hipError_t rc = hipLaunchCooperativeKernel((void*)chunk_fused_kernel,
                                               dim3(BH*NCH), dim3(256), kargs, 0, stream);
    if (rc != hipSuccess){
      (void)hipGetLastError();   // clear sticky error from rejected coop launch
      transform_sums_kernel<<<dim3(BH*NCH), dim3(256), 0, stream>>>(qkvb, cb, qc, kc, vtc, Stc, ksc);
      chunk_prefix_kernel<<<dim3(128), dim3(256), 0, stream>>>(Stc, ksc);
      chunk_out_kernel<<<dim3(BH*NCH), dim3(256), 0, stream>>>(qc, kc, vtc, Stc, ksc, attn);
    }
  }
  gemm_mfma<true><<<dim3(D_/128, M_/128), dim3(256), 0, stream>>>(attn, owb, b_out, midb, M_, D_, D_);
  rmsnorm_kernel<<<dim3(M_), dim3(256), 0, stream>>>(midb, gnorm, out);
}

// Round 10
// 176.785 us; speedup vs baseline: 3.9830x; 3.9830x over previous
//
#include <hip/hip_runtime.h>

typedef unsigned short u16;
typedef unsigned int u32;

#define B_ 2
#define L_ 4096
#define D_ 512
#define H_ 8
#define E_ 64
#define M_ (B_*L_)        // 8192 rows
#define TD (3*D_)         // 1536
#define NCH (L_/64)       // 64 chunks of 64 per sequence
#define BH (B_*H_)        // 16

typedef short bf16x8 __attribute__((ext_vector_type(8)));
typedef float f32x4 __attribute__((ext_vector_type(4)));

__device__ __forceinline__ float bf2f(u16 u){ return __uint_as_float(((u32)u)<<16); }
__device__ __forceinline__ u16 f2bf(float f){
  u32 u = __float_as_uint(f);
  u32 r = u + 0x7FFFu + ((u>>16)&1u);   // RNE; inputs finite
  return (u16)(r>>16);
}
__device__ __forceinline__ float elu1(float v){ return v>0.f ? v+1.f : expf(v); }

__device__ __forceinline__ void async_ld16(const u16* g, u16* l){
  __builtin_amdgcn_global_load_lds(
      (const __attribute__((address_space(1))) void*)g,
      (__attribute__((address_space(3))) void*)l, 16, 0, 0);
}

// ---------------- K1: decay logits + x->bf16 + weight conversions ----------------
__global__ __launch_bounds__(256) void decay_conv_kernel(const float* __restrict__ x,
    const float* __restrict__ dw, const float* __restrict__ db,
    const float* __restrict__ qw, const float* __restrict__ ow,
    float* __restrict__ ll, u16* __restrict__ xb,
    u16* __restrict__ qwb, u16* __restrict__ owb)
{
  int blk = blockIdx.x;
  if (blk < 2048){
    int wv = threadIdx.x>>6, lane = threadIdx.x&63;
    int m = blk*4 + wv;
    float xr[8];
    #pragma unroll
    for (int i=0;i<8;i++) xr[i] = x[(size_t)m*D_ + lane + 64*i];
    #pragma unroll
    for (int i=0;i<8;i++) xb[(size_t)m*D_ + lane + 64*i] = f2bf(xr[i]);
    int b = m >> 12, l = m & (L_-1);
    for (int h=0; h<H_; h++){
      float acc = 0.f;
      #pragma unroll
      for (int i=0;i<8;i++) acc += xr[i]*dw[h*D_ + lane + 64*i];
      #pragma unroll
      for (int off=32; off>0; off>>=1) acc += __shfl_xor(acc, off);
      if (lane == h){
        float z = acc + db[h];
        float lam = 0.9f + 0.1f/(1.f + expf(-z));
        ll[((b*H_+h)*L_) + l] = logf(lam);
      }
    }
  } else {
    int gid = (blk-2048)*256 + threadIdx.x;
    const float* src; u16* dst; int off;
    if (gid < 196608){ src = qw; dst = qwb; off = gid; }
    else { src = ow; dst = owb; off = gid - 196608; }
    float4 v = ((const float4*)src)[off];
    ushort4 o; o.x=f2bf(v.x); o.y=f2bf(v.y); o.z=f2bf(v.z); o.w=f2bf(v.w);
    ((ushort4*)dst)[off] = o;
  }
}

// ---------------- K2: inclusive scan over L (shfl-based), clip to [-50,50] ----------------
__global__ __launch_bounds__(256) void scan_kernel(const float* __restrict__ ll,
    float* __restrict__ cb)
{
  int bh = blockIdx.x, t = threadIdx.x;
  int lane = t & 63, wv = t >> 6;
  const float* p = ll + (size_t)bh*L_ + t*16;
  float s[16];
  #pragma unroll
  for (int q=0;q<4;q++){
    float4 v = *(const float4*)(p + q*4);
    s[q*4+0]=v.x; s[q*4+1]=v.y; s[q*4+2]=v.z; s[q*4+3]=v.w;
  }
  #pragma unroll
  for (int i=1;i<16;i++) s[i] += s[i-1];
  float tot = s[15];
  float ws = tot;
  #pragma unroll
  for (int off=1; off<64; off<<=1){
    float tmp = __shfl_up(ws, off);
    if (lane >= off) ws += tmp;
  }
  __shared__ float wsum[4];
  if (lane == 63) wsum[wv] = ws;
  __syncthreads();
  float base = 0.f;
  #pragma unroll
  for (int w2=0; w2<3; w2++) if (w2 < wv) base += wsum[w2];
  float ex = base + ws - tot;
  float* c = cb + (size_t)bh*L_ + t*16;
  #pragma unroll
  for (int i=0;i<16;i++) c[i] = fminf(50.f, fmaxf(-50.f, ex + s[i]));
}

// ---------------- K3: fused QKV GEMM (64x192 per chunk-head) + transform + St ----------------
// bid = bh*64 + ch.  Computes q~,k~,v for the chunk, writes qc/kc/vtc/Stc/ksc. No qkvb.
__global__ __launch_bounds__(256) void qkv_chunk_kernel(
    const u16* __restrict__ xb, const u16* __restrict__ qwb,
    const float* __restrict__ b_qkv, const float* __restrict__ cb,
    u16* __restrict__ qc, u16* __restrict__ kc, u16* __restrict__ vtc,
    u16* __restrict__ Stc, float* __restrict__ ksc)
{
  int bid = blockIdx.x;
  int bh = bid >> 6, ch = bid & 63;
  int b = bh >> 3, h = bh & 7;
  __shared__ u16 pool[8192];     // K-loop: A(2048 u16)+B(6144 u16); later: Ktl(4096)+Vtl(4096)
  __shared__ u16 Qs[64*68], Ks[64*68], Vs[64*68];
  __shared__ float eqcl[64], ekcl[64], ksr[256];
  int t = threadIdx.x, w = t>>6, lane = t&63;
  int r16 = lane&15, q4 = lane>>4, q8 = q4*8;
  size_t mbase = (size_t)b*L_ + ch*64;
  if (t < 64){
    float c = cb[(size_t)bh*L_ + ch*64 + t];
    eqcl[t] = 0.125f*expf(c);
    ekcl[t] = expf(-c);
  }
  // staging addresses: 16 issues of 16 rows x 32 k; wave w owns issues w*4..w*4+3
  // combined row space: rows 0..63 = A (chunk rows), rows 64..255 = B (192 weight rows of this head)
  const u16* gsrc[4];
  #pragma unroll
  for (int q=0;q<4;q++){
    int ci = w*4 + q;
    int row = ci*16 + (lane>>2);
    int kl = (lane&3)*8;
    if (ci < 4){
      gsrc[q] = xb + (mbase + row)*(size_t)D_ + kl;
    } else {
      int wrow = row - 64;
      int sec = wrow >> 6, e = wrow & 63;
      gsrc[q] = qwb + (size_t)(sec*D_ + h*64 + e)*D_ + kl;
    }
  }
  f32x4 acc[4][3] = {};
  for (int k0=0; k0<D_; k0+=32){
    #pragma unroll
    for (int q=0;q<4;q++)
      async_ld16(gsrc[q] + k0, pool + (w*4+q)*512);
    __syncthreads();
    bf16x8 af[4], bf[3];
    #pragma unroll
    for (int i=0;i<4;i++) af[i] = *(const bf16x8*)&pool[(i*16 + r16)*32 + q8];
    #pragma unroll
    for (int j=0;j<3;j++) bf[j] = *(const bf16x8*)&pool[2048 + (w*48 + j*16 + r16)*32 + q8];
    #pragma unroll
    for (int i=0;i<4;i++)
      #pragma unroll
      for (int j=0;j<3;j++)
        acc[i][j] = __builtin_amdgcn_mfma_f32_16x16x32_bf16(af[i], bf[j], acc[i][j], 0,0,0);
    __syncthreads();
  }
  // epilogue: bias + elu/decay transform, write padded row-major LDS
  #pragma unroll
  for (int j=0;j<3;j++){
    int ncol = w*48 + j*16 + r16;
    int sec = ncol >> 6, e = ncol & 63;      // sec wave-uniform per (w,j)
    float bv = b_qkv[sec*D_ + h*64 + e];
    u16* dst = (sec==0) ? Qs : (sec==1) ? Ks : Vs;
    #pragma unroll
    for (int i=0;i<4;i++)
      #pragma unroll
      for (int r=0;r<4;r++){
        int l = i*16 + q4*4 + r;
        float val = acc[i][j][r] + bv;
        float o;
        if (sec==0)      o = elu1(val)*eqcl[l];
        else if (sec==1) o = elu1(val)*ekcl[l];
        else             o = val;
        dst[l*68 + e] = f2bf(o);
      }
  }
  __syncthreads();
  // write qc/kc (chunked row-major) from Qs/Ks, vectorized
  #pragma unroll
  for (int i=0;i<2;i++){
    int idx = t + 256*i;
    int l = idx>>3, e0 = (idx&7)*8;
    int kh = e0>>5, ej = e0&31;
    ushort4 a0 = *(const ushort4*)&Qs[l*68+e0];
    ushort4 a1 = *(const ushort4*)&Qs[l*68+e0+4];
    u16* qd = qc + ((size_t)bid*2 + kh)*2048 + l*32 + ej;
    *(ushort4*)qd = a0; *(ushort4*)(qd+4) = a1;
    ushort4 b0 = *(const ushort4*)&Ks[l*68+e0];
    ushort4 b1 = *(const ushort4*)&Ks[l*68+e0+4];
    u16* kd = kc + ((size_t)bid*2 + kh)*2048 + l*32 + ej;
    *(ushort4*)kd = b0; *(ushort4*)(kd+4) = b1;
  }
  // transpose K,V into pool (safe: all pool fragment reads completed pre-barrier)
  u16* Ktl = pool;
  u16* Vtl = pool + 4096;
  {
    int e = t & 63, jq = t >> 6;
    u16 kv[16], vv[16];
    float ksum = 0.f;
    #pragma unroll
    for (int jj=0;jj<16;jj++){
      int j = jq*16+jj;
      kv[jj] = Ks[j*68 + e];
      ksum += bf2f(kv[jj]);
      vv[jj] = Vs[j*68 + e];
    }
    int kh = jq>>1, jl = (jq&1)*16;
    u16* kt = &Ktl[(kh*64 + e)*32 + jl];
    u16* vt = &Vtl[(kh*64 + e)*32 + jl];
    #pragma unroll
    for (int s=0;s<4;s++){
      *(ushort4*)(kt + s*4) = *(ushort4*)&kv[s*4];
      *(ushort4*)(vt + s*4) = *(ushort4*)&vv[s*4];
    }
    ksr[t] = ksum;
  }
  __syncthreads();
  // Vtl -> global (chunked layout)
  *(uint4*)&vtc[(size_t)bid*4096 + t*8]        = *(const uint4*)&Vtl[t*8];
  *(uint4*)&vtc[(size_t)bid*4096 + 2048 + t*8] = *(const uint4*)&Vtl[2048 + t*8];
  // St[f][e] = sum_j Vt[f][j] Kt[e][j]
  {
    bf16x8 av[2];
    #pragma unroll
    for (int kh=0;kh<2;kh++)
      av[kh] = *(const bf16x8*)&Vtl[(kh*64 + w*16 + r16)*32 + q8];
    f32x4 sacc[4] = {};
    #pragma unroll
    for (int et=0;et<4;et++)
      #pragma unroll
      for (int kh=0;kh<2;kh++){
        bf16x8 bv = *(const bf16x8*)&Ktl[(kh*64 + et*16 + r16)*32 + q8];
        sacc[et] = __builtin_amdgcn_mfma_f32_16x16x32_bf16(av[kh], bv, sacc[et], 0,0,0);
      }
    #pragma unroll
    for (int et=0;et<4;et++){
      int eh = et>>1, el = (et&1)*16 + r16;
      #pragma unroll
      for (int r=0;r<4;r++){
        int f = w*16 + q4*4 + r;
        Stc[((size_t)bid*2 + eh)*2048 + f*32 + el] = f2bf(sacc[et][r]);
      }
    }
  }
  if (t < 64) ksc[bid*64 + t] = ksr[t] + ksr[64+t] + ksr[128+t] + ksr[192+t];
}

// ---------------- K5: exclusive prefix over chunks (u32-packed bf16 pairs) ----------------
__global__ __launch_bounds__(256) void chunk_prefix_kernel(u16* __restrict__ Stc,
    float* __restrict__ ksc)
{
  int gid = blockIdx.x*256 + threadIdx.x;
  int bh = gid >> 11, e2 = gid & 2047;
  u32* p = (u32*)Stc + (size_t)bh*131072 + e2;
  float r0 = 0.f, r1 = 0.f;
  #pragma unroll 4
  for (int ch=0; ch<NCH; ch++){
    u32 v = p[ch*2048];
    float lo = bf2f((u16)(v & 0xffffu));
    float hi = bf2f((u16)(v >> 16));
    p[ch*2048] = (u32)f2bf(r0) | ((u32)f2bf(r1) << 16);
    r0 += lo; r1 += hi;
  }
  if (gid < BH*64){
    int bh2 = gid >> 6, e = gid & 63;
    float* kp = ksc + bh2*4096 + e;
    float kr = 0.f;
    #pragma unroll 4
    for (int ch=0; ch<NCH; ch++){
      float v = kp[ch*64]; kp[ch*64] = kr; kr += v;
    }
  }
}

// ---------------- K6: chunk output via MFMA (round-7 verified) ----------------
__global__ __launch_bounds__(256) void chunk_out_kernel(const u16* __restrict__ qc,
    const u16* __restrict__ kc, const u16* __restrict__ vtc,
    const u16* __restrict__ Stc, const float* __restrict__ ksc,
    u16* __restrict__ attn)
{
  int bid = blockIdx.x;
  int bh = bid >> 6, ch = bid & 63;
  int b = bh >> 3, h = bh & 7;
  __shared__ u16 KV[16384];
  __shared__ u16 Ab[4096];
  __shared__ float kp[64], den4[256], den[64];
  int t = threadIdx.x, w = t>>6, lane = t&63;
  size_t mbase = (size_t)b*L_ + ch*64;
  const u16* srcs[4] = { qc, kc, vtc, Stc };
  {
    const u16* gbase = srcs[w] + (size_t)bid*4096 + lane*8;
    #pragma unroll
    for (int q=0;q<8;q++)
      async_ld16(gbase + q*512, KV + w*4096 + q*512);
  }
  if (t < 64) kp[t] = ksc[bid*64 + t];
  __syncthreads();
  const u16* Qs   = KV;
  const u16* Kb_s = KV + 4096;
  const u16* Vt_s = KV + 8192;
  const u16* St_s = KV + 12288;
  int r16 = lane & 15, q8 = (lane>>4)*8;
  bf16x8 aq[2];
  #pragma unroll
  for (int eh=0;eh<2;eh++)
    aq[eh] = *(const bf16x8*)&Qs[(eh*64 + w*16 + r16)*32 + q8];
  f32x4 accA[4] = {};
  #pragma unroll
  for (int jt=0;jt<4;jt++)
    #pragma unroll
    for (int eh=0;eh<2;eh++){
      bf16x8 bv = *(const bf16x8*)&Kb_s[(eh*64 + jt*16 + r16)*32 + q8];
      accA[jt] = __builtin_amdgcn_mfma_f32_16x16x32_bf16(aq[eh], bv, accA[jt], 0,0,0);
    }
  int l4 = t>>2, q4 = t&3;
  float dkp = 0.f;
  {
    int eh = q4>>1, el0 = (q4&1)*16;
    bf16x8 x1 = *(const bf16x8*)&Qs[(eh*64 + l4)*32 + el0];
    bf16x8 x2 = *(const bf16x8*)&Qs[(eh*64 + l4)*32 + el0 + 8];
    #pragma unroll
    for (int i=0;i<8;i++)
      dkp += bf2f((u16)x1[i])*kp[q4*16+i] + bf2f((u16)x2[i])*kp[q4*16+8+i];
  }
  #pragma unroll
  for (int jt=0;jt<4;jt++)
    #pragma unroll
    for (int r=0;r<4;r++){
      int lr = w*16 + ((lane>>4)<<2) + r;
      int j  = jt*16 + r16;
      Ab[((jt>>1)*64 + lr)*32 + (jt&1)*16 + r16] = (j <= lr) ? f2bf(accA[jt][r]) : (u16)0;
    }
  __syncthreads();
  float dA = 0.f;
  {
    int jh2 = q4>>1, jl0 = (q4&1)*16;
    bf16x8 y1 = *(const bf16x8*)&Ab[(jh2*64 + l4)*32 + jl0];
    bf16x8 y2 = *(const bf16x8*)&Ab[(jh2*64 + l4)*32 + jl0 + 8];
    #pragma unroll
    for (int i=0;i<8;i++) dA += bf2f((u16)y1[i]) + bf2f((u16)y2[i]);
  }
  den4[t] = dkp + dA;
  __syncthreads();
  if (t < 64) den[t] = den4[t*4] + den4[t*4+1] + den4[t*4+2] + den4[t*4+3] + 1e-6f;
  bf16x8 aA[2];
  #pragma unroll
  for (int jh=0;jh<2;jh++)
    aA[jh] = *(const bf16x8*)&Ab[(jh*64 + w*16 + r16)*32 + q8];
  f32x4 acc[4] = {};
  #pragma unroll
  for (int ft=0;ft<4;ft++){
    #pragma unroll
    for (int jh=0;jh<2;jh++){
      bf16x8 bv = *(const bf16x8*)&Vt_s[(jh*64 + ft*16 + r16)*32 + q8];
      acc[ft] = __builtin_amdgcn_mfma_f32_16x16x32_bf16(aA[jh], bv, acc[ft], 0,0,0);
    }
    #pragma unroll
    for (int eh=0;eh<2;eh++){
      bf16x8 bv = *(const bf16x8*)&St_s[(eh*64 + ft*16 + r16)*32 + q8];
      acc[ft] = __builtin_amdgcn_mfma_f32_16x16x32_bf16(aq[eh], bv, acc[ft], 0,0,0);
    }
  }
  __syncthreads();
  float inv[4];
  #pragma unroll
  for (int r=0;r<4;r++) inv[r] = 1.f / den[w*16 + ((lane>>4)<<2) + r];
  #pragma unroll
  for (int ft=0;ft<4;ft++)
    #pragma unroll
    for (int r=0;r<4;r++){
      int lr = w*16 + ((lane>>4)<<2) + r;
      attn[(mbase + lr)*D_ + h*64 + ft*16 + r16] = f2bf(acc[ft][r]*inv[r]);
    }
}

// ---------------- MFMA GEMM (out-projection): C = A W^T + bias, bf16 out ----------------
__global__ __launch_bounds__(256) void gemm_mfma(const u16* __restrict__ A,
    const u16* __restrict__ W, const float* __restrict__ bias,
    u16* __restrict__ C, int M, int N, int K)
{
  __shared__ u16 As[128*32];
  __shared__ u16 Bs[128*32];
  int n0 = blockIdx.x*128, m0 = blockIdx.y*128;
  int t = threadIdx.x, wave = t>>6, lane = t&63;
  int wm = (wave>>1)*64, wn = (wave&1)*64;
  f32x4 acc[4][4] = {};
  int srow = wave*32 + (lane>>2);
  int scol = (lane&3)*8;
  const u16* gA = A + (size_t)(m0+srow)*K + scol;
  const u16* gB = W + (size_t)(n0+srow)*K + scol;
  u16* lA = As + wave*1024;
  u16* lB = Bs + wave*1024;
  int q8 = (lane>>4)*8, r16 = lane&15;
  for (int k0=0; k0<K; k0+=32){
    async_ld16(gA + k0,                lA);
    async_ld16(gA + k0 + 16*(size_t)K, lA + 512);
    async_ld16(gB + k0,                lB);
    async_ld16(gB + k0 + 16*(size_t)K, lB + 512);
    __syncthreads();
    bf16x8 af[4], bfr[4];
    #pragma unroll
    for (int i=0;i<4;i++) af[i]  = *(const bf16x8*)&As[(wm + i*16 + r16)*32 + q8];
    #pragma unroll
    for (int j=0;j<4;j++) bfr[j] = *(const bf16x8*)&Bs[(wn + j*16 + r16)*32 + q8];
    #pragma unroll
    for (int i=0;i<4;i++)
      #pragma unroll
      for (int j=0;j<4;j++)
        acc[i][j] = __builtin_amdgcn_mfma_f32_16x16x32_bf16(af[i], bfr[j], acc[i][j], 0,0,0);
    __syncthreads();
  }
  #pragma unroll
  for (int i=0;i<4;i++){
    int row = m0 + wm + i*16 + (lane>>4)*4;
    #pragma unroll
    for (int j=0;j<4;j++){
      int col = n0 + wn + j*16 + r16;
      float bv = bias[col];
      #pragma unroll
      for (int r=0;r<4;r++)
        C[(size_t)(row+r)*N + col] = f2bf(acc[i][j][r] + bv);
    }
  }
}

// ---------------- K8: RMSNorm + scale (bf16 mid -> fp32 out) ----------------
__global__ __launch_bounds__(256) void rmsnorm_kernel(const u16* __restrict__ mid,
    const float* __restrict__ scale, float* __restrict__ out)
{
  int m = blockIdx.x, t = threadIdx.x;
  const u16* row = mid + (size_t)m*D_;
  float v0 = bf2f(row[t]), v1 = bf2f(row[t+256]);
  float ss = v0*v0 + v1*v1;
  #pragma unroll
  for (int off=32; off>0; off>>=1) ss += __shfl_xor(ss, off);
  __shared__ float red[4];
  if ((t&63)==0) red[t>>6] = ss;
  __syncthreads();
  float tot = red[0]+red[1]+red[2]+red[3];
  float r = rsqrtf(tot*(1.f/512.f) + 1e-8f);
  out[(size_t)m*D_ + t]       = v0*r*scale[t];
  out[(size_t)m*D_ + t + 256] = v1*r*scale[t+256];
}

extern "C" void kernel_launch(void* const* d_in, const int* in_sizes, int n_in,
                              void* d_out, int out_size, void* d_ws, size_t ws_size,
                              hipStream_t stream)
{
  const float* x     = (const float*)d_in[0];
  const float* w_qkv = (const float*)d_in[1];
  const float* b_qkv = (const float*)d_in[2];
  const float* w_out = (const float*)d_in[3];
  const float* b_out = (const float*)d_in[4];
  const float* w_dec = (const float*)d_in[5];
  const float* b_dec = (const float*)d_in[6];
  const float* gnorm = (const float*)d_in[7];
  float* out = (float*)d_out;

  char* ws = (char*)d_ws;
  u16*   qc   = (u16*)(ws);                    //  8,388,608  (midb reuses after chunk_out)
  u16*   kc   = (u16*)(ws +  8388608);         //  8,388,608
  u16*   vtc  = (u16*)(ws + 16777216);         //  8,388,608
  u16*   Stc  = (u16*)(ws + 25165824);         //  8,388,608
  float* ksc  = (float*)(ws + 33554432);       //    262,144
  float* ll   = (float*)(ws + 33816576);       //    262,144
  float* cb   = (float*)(ws + 34078720);       //    262,144
  u16*   xb   = (u16*)(ws + 34340864);         //  8,388,608  (attn reuses after qkv_chunk)
  u16*   qwb  = (u16*)(ws + 42729472);         //  1,572,864
  u16*   owb  = (u16*)(ws + 44302336);         //    524,288  total 44,826,624
  u16*   attn = xb;
  u16*   midb = qc;

  decay_conv_kernel<<<dim3(3072), dim3(256), 0, stream>>>(x, w_dec, b_dec, w_qkv, w_out,
                                                          ll, xb, qwb, owb);
  scan_kernel<<<dim3(BH), dim3(256), 0, stream>>>(ll, cb);
  qkv_chunk_kernel<<<dim3(BH*NCH), dim3(256), 0, stream>>>(xb, qwb, b_qkv, cb,
                                                           qc, kc, vtc, Stc, ksc);
  chunk_prefix_kernel<<<dim3(128), dim3(256), 0, stream>>>(Stc, ksc);
  chunk_out_kernel<<<dim3(BH*NCH), dim3(256), 0, stream>>>(qc, kc, vtc, Stc, ksc, attn);
  gemm_mfma<<<dim3(D_/128, M_/128), dim3(256), 0, stream>>>(attn, owb, b_out, midb, M_, D_, D_);
  rmsnorm_kernel<<<dim3(M_), dim3(256), 0, stream>>>(midb, gnorm, out);
}